// Round 4
// baseline (144.260 us; speedup 1.0000x reference)
//
#include <hip/hip_runtime.h>

// MergeLayer: out = sigmoid(relu([z[e0]; z[e1]] @ W1 + b1) @ W2 + b2)
// Factored: g = z @ Wcat (+b1 on gi half)  -- node-level GEMM via bf16 MFMA
//           out[k] = sigmoid(dot(relu(gi[e0]+gj[e1]), W2) + b2)  -- edge gather
//
// Round-4: two fixes to the bucketed pipeline.
// (a) edge_bucket: LDS counting-sort per 2048-edge block -> per-bucket global
//     ranges reserved with ONE atomicAdd/bin, records flushed as sorted
//     coalesced runs (~128B bursts). Kills the ~8x write amplification of the
//     round-3 scatter (64 lanes -> 64 bucket regions).
// (b) edge_mlp_b: flattened per-XCD loop over all NBJ buckets via register
//     prefix-scan (static-index unrolled), killing the per-phase tail
//     quantization (9375 edges vs 8192 groups = 43% idle). NBJ=16 keeps the
//     instantaneous per-XCD L2 set ~3.2MB < 4MB despite fuzzy phase bounds.
// Bin keys via float-reciprocal mul: mis-binning affects locality only
// (records carry true i,j). Per-edge arithmetic unchanged.
//
// ws layout: gi | gj | Wt | counters(129 u32 pad) | records(128*cap) | ovfl

#define DD 128
#define NBI 8
#define NBJ 16
#define NBK (NBI * NBJ)
#define OVCAP 16384
#define SCHUNK 2048

typedef __attribute__((ext_vector_type(8))) short short8;
typedef __attribute__((ext_vector_type(4))) float floatx4;

static __device__ __forceinline__ unsigned short f2bf(float f) {
  unsigned int u = __builtin_bit_cast(unsigned int, f);
  u += 0x7fffu + ((u >> 16) & 1u);   // round-to-nearest-even
  return (unsigned short)(u >> 16);
}
static __device__ __forceinline__ float bflo(unsigned int u) {
  return __builtin_bit_cast(float, u << 16);
}
static __device__ __forceinline__ float bfhi(unsigned int u) {
  return __builtin_bit_cast(float, u & 0xffff0000u);
}

// ---------- prelude: Wt[c][k] = Wcat[k][c] as bf16; also zero bucket counters
__global__ __launch_bounds__(256) void wt_build(
    const float* __restrict__ W1, unsigned short* __restrict__ Wt,
    unsigned int* __restrict__ counters) {
  if (counters && blockIdx.x == 0 && threadIdx.x <= NBK)
    counters[threadIdx.x] = 0u;   // NBK bucket cursors + overflow count
  const int g = blockIdx.x * 256 + threadIdx.x;  // 8192 threads total
  const int c = g >> 5;                          // 0..255
  const int kq = (g & 31) * 4;                   // 0..124
  const float* src = (c < 128) ? (W1 + c) : (W1 + 128 * 128 + (c - 128));
  ushort4 o;
  o.x = f2bf(src[(size_t)(kq + 0) * 128]);
  o.y = f2bf(src[(size_t)(kq + 1) * 128]);
  o.z = f2bf(src[(size_t)(kq + 2) * 128]);
  o.w = f2bf(src[(size_t)(kq + 3) * 128]);
  *(ushort4*)&Wt[c * 128 + kq] = o;
}

// ---------- node GEMM via mfma_f32_16x16x32_bf16 (A=W, B=z) ------------------
__global__ __launch_bounds__(256) void node_mfma(
    const float* __restrict__ z, const unsigned short* __restrict__ Wt,
    const float* __restrict__ b1, unsigned short* __restrict__ gi,
    unsigned short* __restrict__ gj, int n_nodes) {
  __shared__ unsigned short zb[64 * 136];  // 17.4 KB; row stride 136
  const int tid = threadIdx.x;
  const int nb = blockIdx.x * 64;

#pragma unroll
  for (int i = 0; i < 8; ++i) {
    int q = tid + i * 256;            // 2048 float4 = 64 nodes x 32
    int nl = q >> 5;
    int node = nb + nl; if (node >= n_nodes) node = n_nodes - 1;
    float4 v = ((const float4*)z)[(size_t)node * 32 + (q & 31)];
    ushort4 o;
    o.x = f2bf(v.x); o.y = f2bf(v.y); o.z = f2bf(v.z); o.w = f2bf(v.w);
    *(ushort4*)&zb[nl * 136 + (q & 31) * 4] = o;
  }

  const int w = tid >> 6, lane = tid & 63;
  const int l15 = lane & 15, quad = lane >> 4;

  short8 a[4][4];
#pragma unroll
  for (int tt = 0; tt < 4; ++tt) {
    const unsigned short* wrow =
        Wt + (size_t)((w * 4 + tt) * 16 + l15) * 128 + quad * 8;
#pragma unroll
    for (int s = 0; s < 4; ++s) a[tt][s] = *(const short8*)(wrow + s * 32);
  }

  floatx4 acc[4][4];  // [tt][nt]
#pragma unroll
  for (int tt = 0; tt < 4; ++tt) {
    floatx4 bias = {0.f, 0.f, 0.f, 0.f};
    if (w < 2) {
      float4 b4 = *(const float4*)&b1[(w * 4 + tt) * 16 + quad * 4];
      bias[0] = b4.x; bias[1] = b4.y; bias[2] = b4.z; bias[3] = b4.w;
    }
#pragma unroll
    for (int nt = 0; nt < 4; ++nt) acc[tt][nt] = bias;
  }

  __syncthreads();

#pragma unroll
  for (int nt = 0; nt < 4; ++nt) {
    short8 bz[4];
#pragma unroll
    for (int s = 0; s < 4; ++s)
      bz[s] = *(const short8*)&zb[(nt * 16 + l15) * 136 + s * 32 + quad * 8];
#pragma unroll
    for (int tt = 0; tt < 4; ++tt)
#pragma unroll
      for (int s = 0; s < 4; ++s)
        acc[tt][nt] =
            __builtin_amdgcn_mfma_f32_16x16x32_bf16(a[tt][s], bz[s], acc[tt][nt], 0, 0, 0);
  }

  unsigned short* base = (w < 2) ? gi : gj;
  const int cbase = w * 64 - ((w < 2) ? 0 : 128);
#pragma unroll
  for (int nt = 0; nt < 4; ++nt) {
    const int node = nb + nt * 16 + l15;
    if (node < n_nodes) {
#pragma unroll
      for (int tt = 0; tt < 4; ++tt) {
        const int c = cbase + tt * 16 + quad * 4;
        ushort4 o;
        o.x = f2bf(acc[tt][nt][0]); o.y = f2bf(acc[tt][nt][1]);
        o.z = f2bf(acc[tt][nt][2]); o.w = f2bf(acc[tt][nt][3]);
        *(ushort4*)&base[(size_t)node * 128 + c] = o;
      }
    }
  }
}

// ---------- edge bucketing: LDS counting-sort, coalesced flush ---------------
// Records pack i|j<<16 (needs n_nodes<=65535) and sb packs t|key<<20 (needs
// E<=2^20); both gated host-side. Mis-binning (float key) is locality-only.
__global__ __launch_bounds__(256) void edge_bucket(
    const int* __restrict__ e, int E, float inv_ci, float inv_cj, int cap,
    unsigned int* __restrict__ counters,   // [0..NBK-1]=cursors, [NBK]=ovfl
    uint2* __restrict__ recs, uint2* __restrict__ ovrecs) {
  __shared__ unsigned int hist[NBK], lbase[NBK], gbase[NBK], cur[NBK];
  __shared__ unsigned int sa[SCHUNK], sb[SCHUNK];
  const int tid = threadIdx.x;
  const int e0 = blockIdx.x * SCHUNK;
  const int nblk = (E - e0 < SCHUNK) ? (E - e0) : SCHUNK;
  if (nblk <= 0) return;   // uniform across block
  for (int k = tid; k < NBK; k += 256) { hist[k] = 0u; cur[k] = 0u; }
  __syncthreads();
  // pass A: histogram
  for (int s = tid; s < nblk; s += 256) {
    const int t = e0 + s;
    const int i = e[t], j = e[E + t];
    int ki = (int)((float)i * inv_ci); if (ki > NBI - 1) ki = NBI - 1;
    int kj = (int)((float)j * inv_cj); if (kj > NBJ - 1) kj = NBJ - 1;
    atomicAdd(&hist[ki * NBJ + kj], 1u);
  }
  __syncthreads();
  if (tid == 0) {   // serial exclusive prefix over 128 bins (cheap)
    unsigned int run = 0;
    for (int k = 0; k < NBK; ++k) { lbase[k] = run; run += hist[k]; }
  }
  __syncthreads();
  if (tid < NBK) {
    const unsigned int h = hist[tid];
    gbase[tid] = h ? atomicAdd(&counters[tid], h) : 0u;
  }
  __syncthreads();
  // pass B: scatter into LDS, sorted by bin (e re-read is L1/L2-hot)
  for (int s = tid; s < nblk; s += 256) {
    const int t = e0 + s;
    const int i = e[t], j = e[E + t];
    int ki = (int)((float)i * inv_ci); if (ki > NBI - 1) ki = NBI - 1;
    int kj = (int)((float)j * inv_cj); if (kj > NBJ - 1) kj = NBJ - 1;
    const int key = ki * NBJ + kj;
    const unsigned int slot = lbase[key] + atomicAdd(&cur[key], 1u);
    sa[slot] = (unsigned int)i | ((unsigned int)j << 16);
    sb[slot] = (unsigned int)t | ((unsigned int)key << 20);
  }
  __syncthreads();
  // flush: consecutive LDS slots in a bin -> consecutive global addresses
  for (int s = tid; s < nblk; s += 256) {
    const unsigned int key = sb[s] >> 20;
    const unsigned int t   = sb[s] & 0xFFFFFu;
    const unsigned int pos = gbase[key] + ((unsigned int)s - lbase[key]);
    uint2 r; r.x = sa[s]; r.y = t;
    if (pos < (unsigned int)cap) {
      recs[(size_t)key * cap + pos] = r;
    } else {
      const unsigned int op = atomicAdd(&counters[NBK], 1u);
      if (op < OVCAP) ovrecs[op] = r;
    }
  }
}

// ---------- edge phase: bucketed, XCD-pinned, flattened, 8 lanes/edge --------
static __device__ __forceinline__ float dot8(uint4 a, uint4 b, float4 w0, float4 w1) {
  float s;
  s = fmaxf(bflo(a.x) + bflo(b.x), 0.f) * w0.x;
  s = fmaf(fmaxf(bfhi(a.x) + bfhi(b.x), 0.f), w0.y, s);
  s = fmaf(fmaxf(bflo(a.y) + bflo(b.y), 0.f), w0.z, s);
  s = fmaf(fmaxf(bfhi(a.y) + bfhi(b.y), 0.f), w0.w, s);
  s = fmaf(fmaxf(bflo(a.z) + bflo(b.z), 0.f), w1.x, s);
  s = fmaf(fmaxf(bfhi(a.z) + bfhi(b.z), 0.f), w1.y, s);
  s = fmaf(fmaxf(bflo(a.w) + bflo(b.w), 0.f), w1.z, s);
  s = fmaf(fmaxf(bfhi(a.w) + bfhi(b.w), 0.f), w1.w, s);
  return s;
}

__global__ __launch_bounds__(256) void edge_mlp_b(
    const unsigned short* __restrict__ gi, const unsigned short* __restrict__ gj,
    const float* __restrict__ W2, const float* __restrict__ b2,
    float* __restrict__ out,
    const unsigned int* __restrict__ counters,
    const uint2* __restrict__ recs, const uint2* __restrict__ ovrecs, int cap) {
  const int p = threadIdx.x & 7;
  const float4* wv = (const float4*)W2;
  const float4 w0 = wv[p * 2],      w1 = wv[p * 2 + 1];
  const float4 w2 = wv[16 + p * 2], w3 = wv[16 + p * 2 + 1];
  const float bias2 = b2[0];

  // blockIdx&7 -> XCD (round-robin dispatch heuristic; perf-only, not corr.)
  const int xcd = blockIdx.x & 7;                 // = i-bucket
  const int g = (blockIdx.x >> 3) * 32 + (threadIdx.x >> 3);  // 0..8191/XCD

  // register prefix over this XCD's NBJ bucket counts (static indices only)
  int pre[NBJ + 1];
  pre[0] = 0;
#pragma unroll
  for (int jb = 0; jb < NBJ; ++jb) {
    int c = (int)counters[xcd * NBJ + jb];
    if (c > cap) c = cap;
    pre[jb + 1] = pre[jb] + c;
  }
  const int total = pre[NBJ];

  for (int t = g; t < total; t += 8192) {
    // locate bucket: unrolled scan, static pre[] indices (no scratch)
    int jb = 0, base = 0;
#pragma unroll
    for (int k = 1; k < NBJ; ++k) {
      if (t >= pre[k]) { jb = k; base = pre[k]; }
    }
    const uint2 r = recs[(size_t)(xcd * NBJ + jb) * cap + (t - base)];
    const int i = (int)(r.x & 0xffffu);
    const int j = (int)(r.x >> 16);
    const uint4* pi = (const uint4*)(gi + (size_t)i * 128);
    const uint4* pj = (const uint4*)(gj + (size_t)j * 128);
    uint4 a0 = pi[p], a1 = pi[8 + p];
    uint4 c0 = pj[p], c1 = pj[8 + p];
    float acc = dot8(a0, c0, w0, w1) + dot8(a1, c1, w2, w3);
    acc += __shfl_xor(acc, 1);
    acc += __shfl_xor(acc, 2);
    acc += __shfl_xor(acc, 4);
    if (p == 0) out[r.y] = 1.f / (1.f + __expf(-(acc + bias2)));
  }

  // overflow safety net (normally empty)
  int ov = (int)counters[NBK]; if (ov > OVCAP) ov = OVCAP;
  for (int t = blockIdx.x * 32 + (threadIdx.x >> 3); t < ov; t += gridDim.x * 32) {
    const uint2 r = ovrecs[t];
    const int i = (int)(r.x & 0xffffu);
    const int j = (int)(r.x >> 16);
    const uint4* pi = (const uint4*)(gi + (size_t)i * 128);
    const uint4* pj = (const uint4*)(gj + (size_t)j * 128);
    uint4 a0 = pi[p], a1 = pi[8 + p];
    uint4 c0 = pj[p], c1 = pj[8 + p];
    float acc = dot8(a0, c0, w0, w1) + dot8(a1, c1, w2, w3);
    acc += __shfl_xor(acc, 1);
    acc += __shfl_xor(acc, 2);
    acc += __shfl_xor(acc, 4);
    if (p == 0) out[r.y] = 1.f / (1.f + __expf(-(acc + bias2)));
  }
}

// ---------- flat edge kernel (fallback: gates not met) ------------------------
__global__ __launch_bounds__(256) void edge_mlp(
    const int* __restrict__ e, const unsigned short* __restrict__ gi,
    const unsigned short* __restrict__ gj, const float* __restrict__ W2,
    const float* __restrict__ b2, float* __restrict__ out, int E) {
  const int p = threadIdx.x & 7;
  const float4* wv = (const float4*)W2;
  const float4 w0 = wv[p * 2],      w1 = wv[p * 2 + 1];
  const float4 w2 = wv[16 + p * 2], w3 = wv[16 + p * 2 + 1];
  const float bias2 = b2[0];
  const int stride = gridDim.x * 32;
  for (int edge = blockIdx.x * 32 + (threadIdx.x >> 3); edge < E; edge += stride) {
    const int i = e[edge];
    const int j = e[E + edge];
    const uint4* pi = (const uint4*)(gi + (size_t)i * 128);
    const uint4* pj = (const uint4*)(gj + (size_t)j * 128);
    uint4 a0 = pi[p], a1 = pi[8 + p];
    uint4 c0 = pj[p], c1 = pj[8 + p];
    float acc = dot8(a0, c0, w0, w1) + dot8(a1, c1, w2, w3);
    acc += __shfl_xor(acc, 1);
    acc += __shfl_xor(acc, 2);
    acc += __shfl_xor(acc, 4);
    if (p == 0) out[edge] = 1.f / (1.f + __expf(-(acc + bias2)));
  }
}

// ---------- fallback (workspace too small): wave per edge ---------------------
__global__ __launch_bounds__(256) void edge_direct(
    const int* __restrict__ e, const float* __restrict__ z,
    const float* __restrict__ W1, const float* __restrict__ b1,
    const float* __restrict__ W2, const float* __restrict__ b2,
    float* __restrict__ out, int E) {
  const int lane = threadIdx.x & 63;
  const int edge = (int)((blockIdx.x * 256u + threadIdx.x) >> 6);
  if (edge >= E) return;
  const int i = e[edge], j = e[E + edge];
  const float* zi = z + (size_t)i * 128;
  const float* zj = z + (size_t)j * 128;
  const int c0 = lane * 2;
  float h0 = b1[c0], h1 = b1[c0 + 1];
  for (int k = 0; k < 128; ++k) {
    float a = zi[k], b = zj[k];
    float2 wt = *(const float2*)&W1[(size_t)k * 128 + c0];
    float2 wb = *(const float2*)&W1[(size_t)(128 + k) * 128 + c0];
    h0 = fmaf(a, wt.x, h0); h1 = fmaf(a, wt.y, h1);
    h0 = fmaf(b, wb.x, h0); h1 = fmaf(b, wb.y, h1);
  }
  float s = fmaxf(h0, 0.f) * W2[c0] + fmaxf(h1, 0.f) * W2[c0 + 1];
#pragma unroll
  for (int off = 1; off < 64; off <<= 1) s += __shfl_xor(s, off);
  if (lane == 0) out[edge] = 1.f / (1.f + __expf(-(s + b2[0])));
}

extern "C" void kernel_launch(void* const* d_in, const int* in_sizes, int n_in,
                              void* d_out, int out_size, void* d_ws, size_t ws_size,
                              hipStream_t stream) {
  const float* z  = (const float*)d_in[0];
  const int*   e  = (const int*)d_in[1];
  const float* W1 = (const float*)d_in[2];
  const float* b1 = (const float*)d_in[3];
  const float* W2 = (const float*)d_in[4];
  const float* b2 = (const float*)d_in[5];
  float* out = (float*)d_out;
  const int n_nodes = in_sizes[0] / DD;  // 50000
  const int E = in_sizes[1] / 2;         // 600000

  const size_t g_bytes = (size_t)n_nodes * DD * sizeof(unsigned short);
  const size_t wt_bytes = 256 * 128 * sizeof(unsigned short);  // 64 KB
  const int cap = E / NBK * 2 + 2048;
  const size_t cnt_bytes = 2048;  // NBK+1 u32, padded
  const size_t rec_bytes = (size_t)NBK * cap * sizeof(uint2);
  const size_t ov_bytes = (size_t)OVCAP * sizeof(uint2);
  const size_t need_bucketed =
      2 * g_bytes + wt_bytes + cnt_bytes + rec_bytes + ov_bytes;

  if (ws_size >= need_bucketed && n_nodes <= 65535 && n_nodes > 0 &&
      E <= (1 << 20)) {
    unsigned short* gi = (unsigned short*)d_ws;
    unsigned short* gj = (unsigned short*)((char*)d_ws + g_bytes);
    unsigned short* Wt = (unsigned short*)((char*)d_ws + 2 * g_bytes);
    unsigned int* counters =
        (unsigned int*)((char*)d_ws + 2 * g_bytes + wt_bytes);
    uint2* recs = (uint2*)((char*)d_ws + 2 * g_bytes + wt_bytes + cnt_bytes);
    uint2* ovrecs = (uint2*)((char*)recs + rec_bytes);
    const int ci = (n_nodes + NBI - 1) / NBI;
    const int cj = (n_nodes + NBJ - 1) / NBJ;
    const float inv_ci = 1.0f / (float)ci;
    const float inv_cj = 1.0f / (float)cj;
    const int bgrid = (E + SCHUNK - 1) / SCHUNK;
    wt_build<<<32, 256, 0, stream>>>(W1, Wt, counters);
    edge_bucket<<<bgrid, 256, 0, stream>>>(e, E, inv_ci, inv_cj, cap, counters,
                                           recs, ovrecs);
    node_mfma<<<(n_nodes + 63) / 64, 256, 0, stream>>>(z, Wt, b1, gi, gj, n_nodes);
    edge_mlp_b<<<2048, 256, 0, stream>>>(gi, gj, W2, b2, out, counters, recs,
                                         ovrecs, cap);
  } else if (ws_size >= 2 * g_bytes + wt_bytes) {
    unsigned short* gi = (unsigned short*)d_ws;
    unsigned short* gj = (unsigned short*)((char*)d_ws + g_bytes);
    unsigned short* Wt = (unsigned short*)((char*)d_ws + 2 * g_bytes);
    wt_build<<<32, 256, 0, stream>>>(W1, Wt, nullptr);
    node_mfma<<<(n_nodes + 63) / 64, 256, 0, stream>>>(z, Wt, b1, gi, gj, n_nodes);
    edge_mlp<<<2048, 256, 0, stream>>>(e, gi, gj, W2, b2, out, E);
  } else {
    edge_direct<<<(E + 3) / 4, 256, 0, stream>>>(e, z, W1, b1, W2, b2, out, E);
  }
}

// Round 5
// 141.699 us; speedup vs baseline: 1.0181x; 1.0181x over previous
//
#include <hip/hip_runtime.h>

// MergeLayer: out = sigmoid(relu([z[e0]; z[e1]] @ W1 + b1) @ W2 + b2)
// Factored: g = z @ Wcat (+b1 on gi half)  -- node-level GEMM via bf16 MFMA
//           out[k] = sigmoid(dot(relu(gi[e0]+gj[e1]), W2) + b2)  -- edge gather
//
// Round-5: collapse the pipeline. Rounds 2-4 showed a ~78us fixed cost per
// iteration (268MB poison fill ~45us + ~10us/launch gaps); the bucketed edge
// win was cancelled by the standalone bucket kernel + extra launch. Fixes:
// (1) wt_build deleted -- node kernel builds A-fragments directly from fp32
//     W1 (scattered L2-hot loads, bit-identical f2bf results).
// (2) bucketing fused into the node kernel (independent work, same LDS
//     reused after a barrier; 7-step parallel prefix replaces serial scan).
// (3) counters zeroed via one hipMemsetAsync.
// Pipeline: memset + node_bucket + edge_mlp_b  (2 kernels, was 4).
// Per-edge arithmetic unchanged.
//
// ws layout: gi | gj | counters(pad 2KB) | records(128*cap uint2) | ovfl

#define DD 128
#define NBI 8
#define NBJ 16
#define NBK (NBI * NBJ)
#define OVCAP 16384
#define SCHUNK 2048

typedef __attribute__((ext_vector_type(8))) short short8;
typedef __attribute__((ext_vector_type(4))) float floatx4;

static __device__ __forceinline__ unsigned short f2bf(float f) {
  unsigned int u = __builtin_bit_cast(unsigned int, f);
  u += 0x7fffu + ((u >> 16) & 1u);   // round-to-nearest-even
  return (unsigned short)(u >> 16);
}
static __device__ __forceinline__ float bflo(unsigned int u) {
  return __builtin_bit_cast(float, u << 16);
}
static __device__ __forceinline__ float bfhi(unsigned int u) {
  return __builtin_bit_cast(float, u & 0xffff0000u);
}

// ---------- K1: node GEMM (frags direct from W1) + fused edge bucketing ------
// Blocks < ntiles: 64-node MFMA tile. Then (same LDS, after barrier)
// blocks < nchunks: 2048-edge LDS counting-sort into 8x16 (i,j) buckets.
__global__ __launch_bounds__(256) void node_bucket(
    const float* __restrict__ z, const float* __restrict__ W1,
    const float* __restrict__ b1, unsigned short* __restrict__ gi,
    unsigned short* __restrict__ gj, int n_nodes,
    const int* __restrict__ e, int E, float inv_ci, float inv_cj, int cap,
    unsigned int* __restrict__ counters,   // [0..NBK-1]=cursors, [NBK]=ovfl
    uint2* __restrict__ recs, uint2* __restrict__ ovrecs,
    int ntiles, int nchunks) {
  // union'd LDS: node zb (64*136 ushort = 17408B) / bucket (20480B)
  __shared__ __align__(16) char smraw[SCHUNK * 8 + 4 * NBK * 4];
  const int tid = threadIdx.x;

  if (blockIdx.x < ntiles) {
    unsigned short* zb = (unsigned short*)smraw;  // row stride 136
    const int nb = blockIdx.x * 64;

    // stage z tile -> bf16 LDS (coalesced float4 reads; 8 per thread)
#pragma unroll
    for (int i = 0; i < 8; ++i) {
      int q = tid + i * 256;            // 2048 float4 = 64 nodes x 32
      int nl = q >> 5;
      int node = nb + nl; if (node >= n_nodes) node = n_nodes - 1;
      float4 v = ((const float4*)z)[(size_t)node * 32 + (q & 31)];
      ushort4 o;
      o.x = f2bf(v.x); o.y = f2bf(v.y); o.z = f2bf(v.z); o.w = f2bf(v.w);
      *(ushort4*)&zb[nl * 136 + (q & 31) * 4] = o;
    }

    const int w = tid >> 6, lane = tid & 63;
    const int l15 = lane & 15, quad = lane >> 4;

    // A fragments straight from fp32 W1 (L2-hot; bit-identical to old Wt):
    // elem m of a[tt][s] = Wcat[quad*8+s*32+m][c], c=(w*4+tt)*16+l15
    short8 a[4][4];
#pragma unroll
    for (int tt = 0; tt < 4; ++tt) {
      const int cc = (w * 4 + tt) * 16 + l15;
      const float* srcb = (w < 2) ? (W1 + cc) : (W1 + 128 * 128 + (cc - 128));
#pragma unroll
      for (int s = 0; s < 4; ++s) {
        short8 av;
#pragma unroll
        for (int m = 0; m < 8; ++m)
          av[m] = (short)f2bf(srcb[(size_t)(quad * 8 + s * 32 + m) * 128]);
        a[tt][s] = av;
      }
    }

    floatx4 acc[4][4];  // [tt][nt]
#pragma unroll
    for (int tt = 0; tt < 4; ++tt) {
      floatx4 bias = {0.f, 0.f, 0.f, 0.f};
      if (w < 2) {  // gi half: b1 folded
        float4 b4 = *(const float4*)&b1[(w * 4 + tt) * 16 + quad * 4];
        bias[0] = b4.x; bias[1] = b4.y; bias[2] = b4.z; bias[3] = b4.w;
      }
#pragma unroll
      for (int nt = 0; nt < 4; ++nt) acc[tt][nt] = bias;
    }

    __syncthreads();

#pragma unroll
    for (int nt = 0; nt < 4; ++nt) {
      short8 bz[4];
#pragma unroll
      for (int s = 0; s < 4; ++s)
        bz[s] = *(const short8*)&zb[(nt * 16 + l15) * 136 + s * 32 + quad * 8];
#pragma unroll
      for (int tt = 0; tt < 4; ++tt)
#pragma unroll
        for (int s = 0; s < 4; ++s)
          acc[tt][nt] = __builtin_amdgcn_mfma_f32_16x16x32_bf16(
              a[tt][s], bz[s], acc[tt][nt], 0, 0, 0);
    }

    unsigned short* base = (w < 2) ? gi : gj;
    const int cbase = w * 64 - ((w < 2) ? 0 : 128);
#pragma unroll
    for (int nt = 0; nt < 4; ++nt) {
      const int node = nb + nt * 16 + l15;
      if (node < n_nodes) {
#pragma unroll
        for (int tt = 0; tt < 4; ++tt) {
          const int c = cbase + tt * 16 + quad * 4;
          ushort4 o;
          o.x = f2bf(acc[tt][nt][0]); o.y = f2bf(acc[tt][nt][1]);
          o.z = f2bf(acc[tt][nt][2]); o.w = f2bf(acc[tt][nt][3]);
          *(ushort4*)&base[(size_t)node * 128 + c] = o;
        }
      }
    }
    __syncthreads();   // node LDS done before bucket reuses it
  }

  // ---- fused bucket phase (independent of node results) ----
  if (blockIdx.x < nchunks) {
    unsigned int* sa    = (unsigned int*)smraw;
    unsigned int* sb    = sa + SCHUNK;
    unsigned int* hist  = sb + SCHUNK;
    unsigned int* lbase = hist + NBK;
    unsigned int* gbase = lbase + NBK;
    unsigned int* cur   = gbase + NBK;
    const int e0 = blockIdx.x * SCHUNK;
    const int nblk = (E - e0 < SCHUNK) ? (E - e0) : SCHUNK;

    for (int k = tid; k < NBK; k += 256) { hist[k] = 0u; cur[k] = 0u; }
    __syncthreads();
    // pass A: histogram
    for (int s = tid; s < nblk; s += 256) {
      const int t = e0 + s;
      const int i = e[t], j = e[E + t];
      int ki = (int)((float)i * inv_ci); if (ki > NBI - 1) ki = NBI - 1;
      int kj = (int)((float)j * inv_cj); if (kj > NBJ - 1) kj = NBJ - 1;
      atomicAdd(&hist[ki * NBJ + kj], 1u);
    }
    __syncthreads();
    // parallel exclusive prefix over 128 bins (Hillis-Steele, 7 steps)
    const unsigned int hv = (tid < NBK) ? hist[tid] : 0u;
    if (tid < NBK) lbase[tid] = hv;
    __syncthreads();
    for (int off = 1; off < NBK; off <<= 1) {
      unsigned int v = 0u;
      if (tid < NBK && tid >= off) v = lbase[tid - off];
      __syncthreads();
      if (tid < NBK) lbase[tid] += v;
      __syncthreads();
    }
    if (tid < NBK) {
      lbase[tid] -= hv;   // inclusive -> exclusive
      gbase[tid] = hv ? atomicAdd(&counters[tid], hv) : 0u;
    }
    __syncthreads();
    // pass B: scatter into LDS sorted by bin (e re-read L1-hot)
    for (int s = tid; s < nblk; s += 256) {
      const int t = e0 + s;
      const int i = e[t], j = e[E + t];
      int ki = (int)((float)i * inv_ci); if (ki > NBI - 1) ki = NBI - 1;
      int kj = (int)((float)j * inv_cj); if (kj > NBJ - 1) kj = NBJ - 1;
      const int key = ki * NBJ + kj;
      const unsigned int slot = lbase[key] + atomicAdd(&cur[key], 1u);
      sa[slot] = (unsigned int)i | ((unsigned int)j << 16);
      sb[slot] = (unsigned int)t | ((unsigned int)key << 20);
    }
    __syncthreads();
    // flush: consecutive LDS slots in a bin -> consecutive global (coalesced)
    for (int s = tid; s < nblk; s += 256) {
      const unsigned int key = sb[s] >> 20;
      const unsigned int t   = sb[s] & 0xFFFFFu;
      const unsigned int pos = gbase[key] + ((unsigned int)s - lbase[key]);
      uint2 r; r.x = sa[s]; r.y = t;
      if (pos < (unsigned int)cap) {
        recs[(size_t)key * cap + pos] = r;
      } else {
        const unsigned int op = atomicAdd(&counters[NBK], 1u);
        if (op < OVCAP) ovrecs[op] = r;
      }
    }
  }
}

// ---------- edge phase: bucketed, XCD-pinned, flattened, 8 lanes/edge --------
static __device__ __forceinline__ float dot8(uint4 a, uint4 b, float4 w0, float4 w1) {
  float s;
  s = fmaxf(bflo(a.x) + bflo(b.x), 0.f) * w0.x;
  s = fmaf(fmaxf(bfhi(a.x) + bfhi(b.x), 0.f), w0.y, s);
  s = fmaf(fmaxf(bflo(a.y) + bflo(b.y), 0.f), w0.z, s);
  s = fmaf(fmaxf(bfhi(a.y) + bfhi(b.y), 0.f), w0.w, s);
  s = fmaf(fmaxf(bflo(a.z) + bflo(b.z), 0.f), w1.x, s);
  s = fmaf(fmaxf(bfhi(a.z) + bfhi(b.z), 0.f), w1.y, s);
  s = fmaf(fmaxf(bflo(a.w) + bflo(b.w), 0.f), w1.z, s);
  s = fmaf(fmaxf(bfhi(a.w) + bfhi(b.w), 0.f), w1.w, s);
  return s;
}

__global__ __launch_bounds__(256) void edge_mlp_b(
    const unsigned short* __restrict__ gi, const unsigned short* __restrict__ gj,
    const float* __restrict__ W2, const float* __restrict__ b2,
    float* __restrict__ out,
    const unsigned int* __restrict__ counters,
    const uint2* __restrict__ recs, const uint2* __restrict__ ovrecs, int cap) {
  const int p = threadIdx.x & 7;
  const float4* wv = (const float4*)W2;
  const float4 w0 = wv[p * 2],      w1 = wv[p * 2 + 1];
  const float4 w2 = wv[16 + p * 2], w3 = wv[16 + p * 2 + 1];
  const float bias2 = b2[0];

  // blockIdx&7 -> XCD (round-robin dispatch heuristic; perf-only, not corr.)
  const int xcd = blockIdx.x & 7;                 // = i-bucket
  const int g = (blockIdx.x >> 3) * 32 + (threadIdx.x >> 3);  // 0..8191/XCD

  // register prefix over this XCD's NBJ bucket counts (static indices only)
  int pre[NBJ + 1];
  pre[0] = 0;
#pragma unroll
  for (int jb = 0; jb < NBJ; ++jb) {
    int c = (int)counters[xcd * NBJ + jb];
    if (c > cap) c = cap;
    pre[jb + 1] = pre[jb] + c;
  }
  const int total = pre[NBJ];

  for (int t = g; t < total; t += 8192) {
    int jb = 0, base = 0;
#pragma unroll
    for (int k = 1; k < NBJ; ++k) {
      if (t >= pre[k]) { jb = k; base = pre[k]; }
    }
    const uint2 r = recs[(size_t)(xcd * NBJ + jb) * cap + (t - base)];
    const int i = (int)(r.x & 0xffffu);
    const int j = (int)(r.x >> 16);
    const uint4* pi = (const uint4*)(gi + (size_t)i * 128);
    const uint4* pj = (const uint4*)(gj + (size_t)j * 128);
    uint4 a0 = pi[p], a1 = pi[8 + p];
    uint4 c0 = pj[p], c1 = pj[8 + p];
    float acc = dot8(a0, c0, w0, w1) + dot8(a1, c1, w2, w3);
    acc += __shfl_xor(acc, 1);
    acc += __shfl_xor(acc, 2);
    acc += __shfl_xor(acc, 4);
    if (p == 0) out[r.y] = 1.f / (1.f + __expf(-(acc + bias2)));
  }

  // overflow safety net (normally empty)
  int ov = (int)counters[NBK]; if (ov > OVCAP) ov = OVCAP;
  for (int t = blockIdx.x * 32 + (threadIdx.x >> 3); t < ov; t += gridDim.x * 32) {
    const uint2 r = ovrecs[t];
    const int i = (int)(r.x & 0xffffu);
    const int j = (int)(r.x >> 16);
    const uint4* pi = (const uint4*)(gi + (size_t)i * 128);
    const uint4* pj = (const uint4*)(gj + (size_t)j * 128);
    uint4 a0 = pi[p], a1 = pi[8 + p];
    uint4 c0 = pj[p], c1 = pj[8 + p];
    float acc = dot8(a0, c0, w0, w1) + dot8(a1, c1, w2, w3);
    acc += __shfl_xor(acc, 1);
    acc += __shfl_xor(acc, 2);
    acc += __shfl_xor(acc, 4);
    if (p == 0) out[r.y] = 1.f / (1.f + __expf(-(acc + bias2)));
  }
}

// ---------- flat edge kernel (fallback: gates not met) ------------------------
__global__ __launch_bounds__(256) void edge_mlp(
    const int* __restrict__ e, const unsigned short* __restrict__ gi,
    const unsigned short* __restrict__ gj, const float* __restrict__ W2,
    const float* __restrict__ b2, float* __restrict__ out, int E) {
  const int p = threadIdx.x & 7;
  const float4* wv = (const float4*)W2;
  const float4 w0 = wv[p * 2],      w1 = wv[p * 2 + 1];
  const float4 w2 = wv[16 + p * 2], w3 = wv[16 + p * 2 + 1];
  const float bias2 = b2[0];
  const int stride = gridDim.x * 32;
  for (int edge = blockIdx.x * 32 + (threadIdx.x >> 3); edge < E; edge += stride) {
    const int i = e[edge];
    const int j = e[E + edge];
    const uint4* pi = (const uint4*)(gi + (size_t)i * 128);
    const uint4* pj = (const uint4*)(gj + (size_t)j * 128);
    uint4 a0 = pi[p], a1 = pi[8 + p];
    uint4 c0 = pj[p], c1 = pj[8 + p];
    float acc = dot8(a0, c0, w0, w1) + dot8(a1, c1, w2, w3);
    acc += __shfl_xor(acc, 1);
    acc += __shfl_xor(acc, 2);
    acc += __shfl_xor(acc, 4);
    if (p == 0) out[edge] = 1.f / (1.f + __expf(-(acc + bias2)));
  }
}

// ---------- fallback (workspace too small): wave per edge ---------------------
__global__ __launch_bounds__(256) void edge_direct(
    const int* __restrict__ e, const float* __restrict__ z,
    const float* __restrict__ W1, const float* __restrict__ b1,
    const float* __restrict__ W2, const float* __restrict__ b2,
    float* __restrict__ out, int E) {
  const int lane = threadIdx.x & 63;
  const int edge = (int)((blockIdx.x * 256u + threadIdx.x) >> 6);
  if (edge >= E) return;
  const int i = e[edge], j = e[E + edge];
  const float* zi = z + (size_t)i * 128;
  const float* zj = z + (size_t)j * 128;
  const int c0 = lane * 2;
  float h0 = b1[c0], h1 = b1[c0 + 1];
  for (int k = 0; k < 128; ++k) {
    float a = zi[k], b = zj[k];
    float2 wt = *(const float2*)&W1[(size_t)k * 128 + c0];
    float2 wb = *(const float2*)&W1[(size_t)(128 + k) * 128 + c0];
    h0 = fmaf(a, wt.x, h0); h1 = fmaf(a, wt.y, h1);
    h0 = fmaf(b, wb.x, h0); h1 = fmaf(b, wb.y, h1);
  }
  float s = fmaxf(h0, 0.f) * W2[c0] + fmaxf(h1, 0.f) * W2[c0 + 1];
#pragma unroll
  for (int off = 1; off < 64; off <<= 1) s += __shfl_xor(s, off);
  if (lane == 0) out[edge] = 1.f / (1.f + __expf(-(s + b2[0])));
}

extern "C" void kernel_launch(void* const* d_in, const int* in_sizes, int n_in,
                              void* d_out, int out_size, void* d_ws, size_t ws_size,
                              hipStream_t stream) {
  const float* z  = (const float*)d_in[0];
  const int*   e  = (const int*)d_in[1];
  const float* W1 = (const float*)d_in[2];
  const float* b1 = (const float*)d_in[3];
  const float* W2 = (const float*)d_in[4];
  const float* b2 = (const float*)d_in[5];
  float* out = (float*)d_out;
  const int n_nodes = in_sizes[0] / DD;  // 50000
  const int E = in_sizes[1] / 2;         // 600000

  const size_t g_bytes = (size_t)n_nodes * DD * sizeof(unsigned short);
  const int cap = E / NBK * 2 + 2048;
  const size_t cnt_bytes = 2048;  // NBK+1 u32, padded
  const size_t rec_bytes = (size_t)NBK * cap * sizeof(uint2);
  const size_t ov_bytes = (size_t)OVCAP * sizeof(uint2);
  const size_t need_bucketed = 2 * g_bytes + cnt_bytes + rec_bytes + ov_bytes;

  const int ntiles = (n_nodes + 63) / 64;
  const int nchunks = (E + SCHUNK - 1) / SCHUNK;

  if (ws_size >= need_bucketed && n_nodes <= 65535 && n_nodes > 0 &&
      E <= (1 << 20)) {
    unsigned short* gi = (unsigned short*)d_ws;
    unsigned short* gj = (unsigned short*)((char*)d_ws + g_bytes);
    unsigned int* counters = (unsigned int*)((char*)d_ws + 2 * g_bytes);
    uint2* recs = (uint2*)((char*)d_ws + 2 * g_bytes + cnt_bytes);
    uint2* ovrecs = (uint2*)((char*)recs + rec_bytes);
    const int ci = (n_nodes + NBI - 1) / NBI;
    const int cj = (n_nodes + NBJ - 1) / NBJ;
    const float inv_ci = 1.0f / (float)ci;
    const float inv_cj = 1.0f / (float)cj;
    const int grid1 = (ntiles > nchunks) ? ntiles : nchunks;
    hipMemsetAsync(counters, 0, cnt_bytes, stream);
    node_bucket<<<grid1, 256, 0, stream>>>(z, W1, b1, gi, gj, n_nodes, e, E,
                                           inv_ci, inv_cj, cap, counters, recs,
                                           ovrecs, ntiles, nchunks);
    edge_mlp_b<<<2048, 256, 0, stream>>>(gi, gj, W2, b2, out, counters, recs,
                                         ovrecs, cap);
  } else if (ws_size >= 2 * g_bytes) {
    unsigned short* gi = (unsigned short*)d_ws;
    unsigned short* gj = (unsigned short*)((char*)d_ws + g_bytes);
    node_bucket<<<ntiles, 256, 0, stream>>>(z, W1, b1, gi, gj, n_nodes, e, E,
                                            1.f, 1.f, 0, nullptr, nullptr,
                                            nullptr, ntiles, /*nchunks=*/0);
    edge_mlp<<<2048, 256, 0, stream>>>(e, gi, gj, W2, b2, out, E);
  } else {
    edge_direct<<<(E + 3) / 4, 256, 0, stream>>>(e, z, W1, b1, W2, b2, out, E);
  }
}

// Round 7
// 138.638 us; speedup vs baseline: 1.0406x; 1.0221x over previous
//
#include <hip/hip_runtime.h>

// MergeLayer: out = sigmoid(relu([z[e0]; z[e1]] @ W1 + b1) @ W2 + b2)
// Factored: g = z @ Wcat (+b1 on gi half)  -- node-level GEMM via bf16 MFMA
//           out[k] = sigmoid(dot(relu(gi[e0]+gj[e1]), W2) + b2)  -- edge gather
//
// Round-7: R6's nontemporal hints caused a correctness FAIL (absmax 0.71):
// nt-stores to `out` bypass L2 while the harness's memset left dirty zero
// lines there -> lost updates. ALL nt hints reverted; every instruction path
// is now identical to previously-passing code:
//   K1 node_direct: MFMA node GEMM, A-fragments direct from fp32 W1 (R5)
//   K2 edge_mlp: persistent flat gather+MLP (R0/R1)
// Bucketing stays deleted: R2-R5 showed the edge phase is cache-line
// request-rate bound (4 x 128B lines/edge is irreducible at bf16), so
// locality prep costs more than it saves.
//
// ws layout: gi (N*128 bf16) | gj (N*128 bf16)

#define DD 128

typedef __attribute__((ext_vector_type(8))) short short8;
typedef __attribute__((ext_vector_type(4))) float floatx4;

static __device__ __forceinline__ unsigned short f2bf(float f) {
  unsigned int u = __builtin_bit_cast(unsigned int, f);
  u += 0x7fffu + ((u >> 16) & 1u);   // round-to-nearest-even
  return (unsigned short)(u >> 16);
}
static __device__ __forceinline__ float bflo(unsigned int u) {
  return __builtin_bit_cast(float, u << 16);
}
static __device__ __forceinline__ float bfhi(unsigned int u) {
  return __builtin_bit_cast(float, u & 0xffff0000u);
}

// ---------- K1: node GEMM via mfma_f32_16x16x32_bf16, frags direct from W1 ---
// Block: 256 threads = 4 waves, 64 nodes (4 node-tiles). Wave w owns channel
// tiles t = 4w..4w+3 (64 channels) for ALL 4 node-tiles.
__global__ __launch_bounds__(256) void node_direct(
    const float* __restrict__ z, const float* __restrict__ W1,
    const float* __restrict__ b1, unsigned short* __restrict__ gi,
    unsigned short* __restrict__ gj, int n_nodes) {
  __shared__ unsigned short zb[64 * 136];  // 17.4 KB; row stride 136
  const int tid = threadIdx.x;
  const int nb = blockIdx.x * 64;

  // stage z tile -> bf16 LDS (coalesced float4 reads; 8 per thread)
#pragma unroll
  for (int i = 0; i < 8; ++i) {
    int q = tid + i * 256;            // 2048 float4 = 64 nodes x 32
    int nl = q >> 5;
    int node = nb + nl; if (node >= n_nodes) node = n_nodes - 1;
    float4 v = ((const float4*)z)[(size_t)node * 32 + (q & 31)];
    ushort4 o;
    o.x = f2bf(v.x); o.y = f2bf(v.y); o.z = f2bf(v.z); o.w = f2bf(v.w);
    *(ushort4*)&zb[nl * 136 + (q & 31) * 4] = o;
  }

  const int w = tid >> 6, lane = tid & 63;
  const int l15 = lane & 15, quad = lane >> 4;

  // A fragments straight from fp32 W1 (L2-hot, reused by all 782 blocks):
  // elem m of a[tt][s] = Wcat[quad*8+s*32+m][c], c=(w*4+tt)*16+l15
  short8 a[4][4];
#pragma unroll
  for (int tt = 0; tt < 4; ++tt) {
    const int cc = (w * 4 + tt) * 16 + l15;
    const float* srcb = (w < 2) ? (W1 + cc) : (W1 + 128 * 128 + (cc - 128));
#pragma unroll
    for (int s = 0; s < 4; ++s) {
      short8 av;
#pragma unroll
      for (int m = 0; m < 8; ++m)
        av[m] = (short)f2bf(srcb[(size_t)(quad * 8 + s * 32 + m) * 128]);
      a[tt][s] = av;
    }
  }

  floatx4 acc[4][4];  // [tt][nt]
#pragma unroll
  for (int tt = 0; tt < 4; ++tt) {
    floatx4 bias = {0.f, 0.f, 0.f, 0.f};
    if (w < 2) {  // gi half: b1 folded; channel = (w*4+tt)*16 + quad*4 + r
      float4 b4 = *(const float4*)&b1[(w * 4 + tt) * 16 + quad * 4];
      bias[0] = b4.x; bias[1] = b4.y; bias[2] = b4.z; bias[3] = b4.w;
    }
#pragma unroll
    for (int nt = 0; nt < 4; ++nt) acc[tt][nt] = bias;
  }

  __syncthreads();

#pragma unroll
  for (int nt = 0; nt < 4; ++nt) {
    short8 bz[4];  // B[k=quad*8+j][n=lane&15], n -> node
#pragma unroll
    for (int s = 0; s < 4; ++s)
      bz[s] = *(const short8*)&zb[(nt * 16 + l15) * 136 + s * 32 + quad * 8];
#pragma unroll
    for (int tt = 0; tt < 4; ++tt)
#pragma unroll
      for (int s = 0; s < 4; ++s)
        acc[tt][nt] = __builtin_amdgcn_mfma_f32_16x16x32_bf16(
            a[tt][s], bz[s], acc[tt][nt], 0, 0, 0);
  }

  // epilogue: col=lane&15 -> node, row=quad*4+r -> channel (4 consecutive)
  unsigned short* base = (w < 2) ? gi : gj;
  const int cbase = w * 64 - ((w < 2) ? 0 : 128);
#pragma unroll
  for (int nt = 0; nt < 4; ++nt) {
    const int node = nb + nt * 16 + l15;
    if (node < n_nodes) {
#pragma unroll
      for (int tt = 0; tt < 4; ++tt) {
        const int c = cbase + tt * 16 + quad * 4;
        ushort4 o;
        o.x = f2bf(acc[tt][nt][0]); o.y = f2bf(acc[tt][nt][1]);
        o.z = f2bf(acc[tt][nt][2]); o.w = f2bf(acc[tt][nt][3]);
        *(ushort4*)&base[(size_t)node * 128 + c] = o;
      }
    }
  }
}

// ---------- K2: edge phase, persistent, 8 lanes per edge, W2 in registers ----
static __device__ __forceinline__ float dot8(uint4 a, uint4 b, float4 w0, float4 w1) {
  float s;
  s = fmaxf(bflo(a.x) + bflo(b.x), 0.f) * w0.x;
  s = fmaf(fmaxf(bfhi(a.x) + bfhi(b.x), 0.f), w0.y, s);
  s = fmaf(fmaxf(bflo(a.y) + bflo(b.y), 0.f), w0.z, s);
  s = fmaf(fmaxf(bfhi(a.y) + bfhi(b.y), 0.f), w0.w, s);
  s = fmaf(fmaxf(bflo(a.z) + bflo(b.z), 0.f), w1.x, s);
  s = fmaf(fmaxf(bfhi(a.z) + bfhi(b.z), 0.f), w1.y, s);
  s = fmaf(fmaxf(bflo(a.w) + bflo(b.w), 0.f), w1.z, s);
  s = fmaf(fmaxf(bfhi(a.w) + bfhi(b.w), 0.f), w1.w, s);
  return s;
}

__global__ __launch_bounds__(256) void edge_mlp(
    const int* __restrict__ e, const unsigned short* __restrict__ gi,
    const unsigned short* __restrict__ gj, const float* __restrict__ W2,
    const float* __restrict__ b2, float* __restrict__ out, int E) {
  const int p = threadIdx.x & 7;
  // W2 chunk for this lane, held in 16 VGPRs (512B table, L2-hot; once/wave)
  const float4* wv = (const float4*)W2;
  const float4 w0 = wv[p * 2],      w1 = wv[p * 2 + 1];
  const float4 w2 = wv[16 + p * 2], w3 = wv[16 + p * 2 + 1];
  const float bias2 = b2[0];

  const int stride = gridDim.x * 32;  // 32 edges per block per iteration
  for (int edge = blockIdx.x * 32 + (threadIdx.x >> 3); edge < E; edge += stride) {
    const int i = e[edge];
    const int j = e[E + edge];
    // 8 lanes x 16B cover each 128B line of the two 256B rows, fully used.
    const uint4* pi = (const uint4*)(gi + (size_t)i * 128);
    const uint4* pj = (const uint4*)(gj + (size_t)j * 128);
    uint4 a0 = pi[p], a1 = pi[8 + p];
    uint4 c0 = pj[p], c1 = pj[8 + p];
    float acc = dot8(a0, c0, w0, w1) + dot8(a1, c1, w2, w3);
    acc += __shfl_xor(acc, 1);
    acc += __shfl_xor(acc, 2);
    acc += __shfl_xor(acc, 4);
    if (p == 0) {
      float x = acc + bias2;
      out[edge] = 1.f / (1.f + __expf(-x));
    }
  }
}

// ---------- fallback (workspace too small): wave per edge ---------------------
__global__ __launch_bounds__(256) void edge_direct(
    const int* __restrict__ e, const float* __restrict__ z,
    const float* __restrict__ W1, const float* __restrict__ b1,
    const float* __restrict__ W2, const float* __restrict__ b2,
    float* __restrict__ out, int E) {
  const int lane = threadIdx.x & 63;
  const int edge = (int)((blockIdx.x * 256u + threadIdx.x) >> 6);
  if (edge >= E) return;
  const int i = e[edge], j = e[E + edge];
  const float* zi = z + (size_t)i * 128;
  const float* zj = z + (size_t)j * 128;
  const int c0 = lane * 2;
  float h0 = b1[c0], h1 = b1[c0 + 1];
  for (int k = 0; k < 128; ++k) {
    float a = zi[k], b = zj[k];
    float2 wt = *(const float2*)&W1[(size_t)k * 128 + c0];
    float2 wb = *(const float2*)&W1[(size_t)(128 + k) * 128 + c0];
    h0 = fmaf(a, wt.x, h0); h1 = fmaf(a, wt.y, h1);
    h0 = fmaf(b, wb.x, h0); h1 = fmaf(b, wb.y, h1);
  }
  float s = fmaxf(h0, 0.f) * W2[c0] + fmaxf(h1, 0.f) * W2[c0 + 1];
#pragma unroll
  for (int off = 1; off < 64; off <<= 1) s += __shfl_xor(s, off);
  if (lane == 0) out[edge] = 1.f / (1.f + __expf(-(s + b2[0])));
}

extern "C" void kernel_launch(void* const* d_in, const int* in_sizes, int n_in,
                              void* d_out, int out_size, void* d_ws, size_t ws_size,
                              hipStream_t stream) {
  const float* z  = (const float*)d_in[0];
  const int*   e  = (const int*)d_in[1];
  const float* W1 = (const float*)d_in[2];
  const float* b1 = (const float*)d_in[3];
  const float* W2 = (const float*)d_in[4];
  const float* b2 = (const float*)d_in[5];
  float* out = (float*)d_out;
  const int n_nodes = in_sizes[0] / DD;  // 50000
  const int E = in_sizes[1] / 2;         // 600000

  const size_t g_bytes = (size_t)n_nodes * DD * sizeof(unsigned short);

  if (ws_size >= 2 * g_bytes && n_nodes > 0) {
    unsigned short* gi = (unsigned short*)d_ws;
    unsigned short* gj = (unsigned short*)((char*)d_ws + g_bytes);
    node_direct<<<(n_nodes + 63) / 64, 256, 0, stream>>>(z, W1, b1, gi, gj,
                                                         n_nodes);
    edge_mlp<<<2048, 256, 0, stream>>>(e, gi, gj, W2, b2, out, E);
  } else {
    edge_direct<<<(E + 3) / 4, 256, 0, stream>>>(e, z, W1, b1, W2, b2, out, E);
  }
}

// Round 8
// 134.156 us; speedup vs baseline: 1.0753x; 1.0334x over previous
//
#include <hip/hip_runtime.h>

// MergeLayer: out = sigmoid(relu([z[e0]; z[e1]] @ W1 + b1) @ W2 + b2)
// Factored: g = z @ Wcat (+b1 on gi half)  -- node-level GEMM via bf16 MFMA
//           out[k] = sigmoid(dot(relu(gi[e0]+gj[e1]), W2) + b2)  -- edge gather
//
// Round-8: R7 measured node_direct at 45.5us (5x off roofline). Two causes:
// (a) W1-direct scalar column loads (my R5 regression) -- fixed by restoring
//     the R0 wt_build + Wt bf16 path (16B L1-hot fragment loads);
// (b) epilogue write scatter (present since R0): each 8B store inst sprays
//     64 chunks across 16 different 256B rows -> partial-line writes into
//     fill-evicted lines -> write-allocate RMW + request amplification.
//     Fixed: after MFMA, zb is dead; stage the g-tile into it per half
//     (gi: waves 0-1, gj: waves 2-3) and emit fully-coalesced 16B
//     full-line global stores. Bit-identical f2bf values, just rerouted.
// Everything else is the proven R0/R7 code verbatim.
//
// ws layout: gi (N*128 bf16) | gj (N*128 bf16) | Wt (256x128 bf16, 64KB)

#define DD 128

typedef __attribute__((ext_vector_type(8))) short short8;
typedef __attribute__((ext_vector_type(4))) float floatx4;

static __device__ __forceinline__ unsigned short f2bf(float f) {
  unsigned int u = __builtin_bit_cast(unsigned int, f);
  u += 0x7fffu + ((u >> 16) & 1u);   // round-to-nearest-even
  return (unsigned short)(u >> 16);
}
static __device__ __forceinline__ float bflo(unsigned int u) {
  return __builtin_bit_cast(float, u << 16);
}
static __device__ __forceinline__ float bfhi(unsigned int u) {
  return __builtin_bit_cast(float, u & 0xffff0000u);
}

// ---------- prelude: Wt[c][k] = Wcat[k][c] as bf16 ---------------------------
// Wcat[k][c] = (c<128) ? W1[k][c] : W1[128+k][c-128];  W1 is [256][128] fp32.
__global__ __launch_bounds__(256) void wt_build(
    const float* __restrict__ W1, unsigned short* __restrict__ Wt) {
  const int g = blockIdx.x * 256 + threadIdx.x;  // 8192 threads total
  const int c = g >> 5;                          // 0..255
  const int kq = (g & 31) * 4;                   // 0..124
  const float* src = (c < 128) ? (W1 + c) : (W1 + 128 * 128 + (c - 128));
  ushort4 o;
  o.x = f2bf(src[(size_t)(kq + 0) * 128]);
  o.y = f2bf(src[(size_t)(kq + 1) * 128]);
  o.z = f2bf(src[(size_t)(kq + 2) * 128]);
  o.w = f2bf(src[(size_t)(kq + 3) * 128]);
  *(ushort4*)&Wt[c * 128 + kq] = o;
}

// ---------- node GEMM via mfma_f32_16x16x32_bf16 (A=W, B=z) ------------------
// Block: 256 threads = 4 waves, 64 nodes (4 node-tiles). Wave w owns channel
// tiles t = 4w..4w+3 (64 channels) for ALL 4 node-tiles.
// NEW epilogue: g-tile staged in LDS (reusing zb) -> coalesced 16B stores.
__global__ __launch_bounds__(256) void node_mfma(
    const float* __restrict__ z, const unsigned short* __restrict__ Wt,
    const float* __restrict__ b1, unsigned short* __restrict__ gi,
    unsigned short* __restrict__ gj, int n_nodes) {
  __shared__ __align__(16) unsigned short zb[64 * 136];  // 17.4 KB
  const int tid = threadIdx.x;
  const int nb = blockIdx.x * 64;

  // stage z tile -> bf16 LDS (coalesced float4 reads; 8 per thread)
#pragma unroll
  for (int i = 0; i < 8; ++i) {
    int q = tid + i * 256;            // 2048 float4 = 64 nodes x 32
    int nl = q >> 5;
    int node = nb + nl; if (node >= n_nodes) node = n_nodes - 1;
    float4 v = ((const float4*)z)[(size_t)node * 32 + (q & 31)];
    ushort4 o;
    o.x = f2bf(v.x); o.y = f2bf(v.y); o.z = f2bf(v.z); o.w = f2bf(v.w);
    *(ushort4*)&zb[nl * 136 + (q & 31) * 4] = o;
  }

  const int w = tid >> 6, lane = tid & 63;
  const int l15 = lane & 15, quad = lane >> 4;

  // A fragments (W): A[m=lane&15][k=quad*8+j]; t_global = w*4+tt (L1-hot Wt)
  short8 a[4][4];
#pragma unroll
  for (int tt = 0; tt < 4; ++tt) {
    const unsigned short* wrow =
        Wt + (size_t)((w * 4 + tt) * 16 + l15) * 128 + quad * 8;
#pragma unroll
    for (int s = 0; s < 4; ++s) a[tt][s] = *(const short8*)(wrow + s * 32);
  }

  floatx4 acc[4][4];  // [tt][nt]
#pragma unroll
  for (int tt = 0; tt < 4; ++tt) {
    floatx4 bias = {0.f, 0.f, 0.f, 0.f};
    if (w < 2) {  // gi half: b1 folded; channel = (w*4+tt)*16 + quad*4 + r
      float4 b4 = *(const float4*)&b1[(w * 4 + tt) * 16 + quad * 4];
      bias[0] = b4.x; bias[1] = b4.y; bias[2] = b4.z; bias[3] = b4.w;
    }
#pragma unroll
    for (int nt = 0; nt < 4; ++nt) acc[tt][nt] = bias;
  }

  __syncthreads();

#pragma unroll
  for (int nt = 0; nt < 4; ++nt) {
    short8 bz[4];  // B[k=quad*8+j][n=lane&15], n -> node
#pragma unroll
    for (int s = 0; s < 4; ++s)
      bz[s] = *(const short8*)&zb[(nt * 16 + l15) * 136 + s * 32 + quad * 8];
#pragma unroll
    for (int tt = 0; tt < 4; ++tt)
#pragma unroll
      for (int s = 0; s < 4; ++s)
        acc[tt][nt] = __builtin_amdgcn_mfma_f32_16x16x32_bf16(
            a[tt][s], bz[s], acc[tt][nt], 0, 0, 0);
  }

  // ---- epilogue: LDS-transposed, fully-coalesced stores ----
  // C layout: col=l15 -> node (nt*16+l15), row=quad*4+r -> channel
  // cbase+tt*16+quad*4+r, cbase=(w&1)*64. Stage per half into zb[64][136],
  // then 256 threads emit contiguous 16B stores (full 64B lines, no RMW).
  __syncthreads();   // all zb reads done; buffer is reusable
#pragma unroll
  for (int half = 0; half < 2; ++half) {
    if ((w >> 1) == half) {   // waves 0,1 produce gi; waves 2,3 produce gj
      const int cbase = (w & 1) * 64;
#pragma unroll
      for (int nt = 0; nt < 4; ++nt) {
        const int row = (nt * 16 + l15) * 136;
#pragma unroll
        for (int tt = 0; tt < 4; ++tt) {
          const int c = cbase + tt * 16 + quad * 4;
          ushort4 o;
          o.x = f2bf(acc[tt][nt][0]); o.y = f2bf(acc[tt][nt][1]);
          o.z = f2bf(acc[tt][nt][2]); o.w = f2bf(acc[tt][nt][3]);
          *(ushort4*)&zb[row + c] = o;
        }
      }
    }
    __syncthreads();
    unsigned short* dst = half ? gj : gi;
    // 64 nodes x 128 ch = 8192 ushort; 4 iters x 256 threads x 8 ushort
#pragma unroll
    for (int it = 0; it < 4; ++it) {
      const int u = tid * 8 + it * 2048;
      const int n = u >> 7, c = u & 127;
      const int node = nb + n;
      ushort4 v0 = *(const ushort4*)&zb[n * 136 + c];
      ushort4 v1 = *(const ushort4*)&zb[n * 136 + c + 4];
      if (node < n_nodes) {
        ushort4* gp = (ushort4*)&dst[(size_t)node * 128 + c];
        gp[0] = v0;
        gp[1] = v1;
      }
    }
    __syncthreads();
  }
}

// ---------- edge phase: persistent, 8 lanes per edge, W2 in registers --------
static __device__ __forceinline__ float dot8(uint4 a, uint4 b, float4 w0, float4 w1) {
  float s;
  s = fmaxf(bflo(a.x) + bflo(b.x), 0.f) * w0.x;
  s = fmaf(fmaxf(bfhi(a.x) + bfhi(b.x), 0.f), w0.y, s);
  s = fmaf(fmaxf(bflo(a.y) + bflo(b.y), 0.f), w0.z, s);
  s = fmaf(fmaxf(bfhi(a.y) + bfhi(b.y), 0.f), w0.w, s);
  s = fmaf(fmaxf(bflo(a.z) + bflo(b.z), 0.f), w1.x, s);
  s = fmaf(fmaxf(bfhi(a.z) + bfhi(b.z), 0.f), w1.y, s);
  s = fmaf(fmaxf(bflo(a.w) + bflo(b.w), 0.f), w1.z, s);
  s = fmaf(fmaxf(bfhi(a.w) + bfhi(b.w), 0.f), w1.w, s);
  return s;
}

__global__ __launch_bounds__(256) void edge_mlp(
    const int* __restrict__ e, const unsigned short* __restrict__ gi,
    const unsigned short* __restrict__ gj, const float* __restrict__ W2,
    const float* __restrict__ b2, float* __restrict__ out, int E) {
  const int p = threadIdx.x & 7;
  // W2 chunk for this lane, held in 16 VGPRs (512B table, L2-hot; once/wave)
  const float4* wv = (const float4*)W2;
  const float4 w0 = wv[p * 2],      w1 = wv[p * 2 + 1];
  const float4 w2 = wv[16 + p * 2], w3 = wv[16 + p * 2 + 1];
  const float bias2 = b2[0];

  const int stride = gridDim.x * 32;  // 32 edges per block per iteration
  for (int edge = blockIdx.x * 32 + (threadIdx.x >> 3); edge < E; edge += stride) {
    const int i = e[edge];
    const int j = e[E + edge];
    // 8 lanes x 16B cover each 128B line of the two 256B rows, fully used.
    const uint4* pi = (const uint4*)(gi + (size_t)i * 128);
    const uint4* pj = (const uint4*)(gj + (size_t)j * 128);
    uint4 a0 = pi[p], a1 = pi[8 + p];
    uint4 c0 = pj[p], c1 = pj[8 + p];
    float acc = dot8(a0, c0, w0, w1) + dot8(a1, c1, w2, w3);
    acc += __shfl_xor(acc, 1);
    acc += __shfl_xor(acc, 2);
    acc += __shfl_xor(acc, 4);
    if (p == 0) {
      float x = acc + bias2;
      out[edge] = 1.f / (1.f + __expf(-x));
    }
  }
}

// ---------- fallback (workspace too small): wave per edge ---------------------
__global__ __launch_bounds__(256) void edge_direct(
    const int* __restrict__ e, const float* __restrict__ z,
    const float* __restrict__ W1, const float* __restrict__ b1,
    const float* __restrict__ W2, const float* __restrict__ b2,
    float* __restrict__ out, int E) {
  const int lane = threadIdx.x & 63;
  const int edge = (int)((blockIdx.x * 256u + threadIdx.x) >> 6);
  if (edge >= E) return;
  const int i = e[edge], j = e[E + edge];
  const float* zi = z + (size_t)i * 128;
  const float* zj = z + (size_t)j * 128;
  const int c0 = lane * 2;
  float h0 = b1[c0], h1 = b1[c0 + 1];
  for (int k = 0; k < 128; ++k) {
    float a = zi[k], b = zj[k];
    float2 wt = *(const float2*)&W1[(size_t)k * 128 + c0];
    float2 wb = *(const float2*)&W1[(size_t)(128 + k) * 128 + c0];
    h0 = fmaf(a, wt.x, h0); h1 = fmaf(a, wt.y, h1);
    h0 = fmaf(b, wb.x, h0); h1 = fmaf(b, wb.y, h1);
  }
  float s = fmaxf(h0, 0.f) * W2[c0] + fmaxf(h1, 0.f) * W2[c0 + 1];
#pragma unroll
  for (int off = 1; off < 64; off <<= 1) s += __shfl_xor(s, off);
  if (lane == 0) out[edge] = 1.f / (1.f + __expf(-(s + b2[0])));
}

extern "C" void kernel_launch(void* const* d_in, const int* in_sizes, int n_in,
                              void* d_out, int out_size, void* d_ws, size_t ws_size,
                              hipStream_t stream) {
  const float* z  = (const float*)d_in[0];
  const int*   e  = (const int*)d_in[1];
  const float* W1 = (const float*)d_in[2];
  const float* b1 = (const float*)d_in[3];
  const float* W2 = (const float*)d_in[4];
  const float* b2 = (const float*)d_in[5];
  float* out = (float*)d_out;
  const int n_nodes = in_sizes[0] / DD;  // 50000
  const int E = in_sizes[1] / 2;         // 600000

  const size_t g_bytes = (size_t)n_nodes * DD * sizeof(unsigned short);
  const size_t wt_bytes = 256 * 128 * sizeof(unsigned short);  // 64 KB

  if (ws_size >= 2 * g_bytes + wt_bytes && n_nodes > 0) {
    unsigned short* gi = (unsigned short*)d_ws;
    unsigned short* gj = (unsigned short*)((char*)d_ws + g_bytes);
    unsigned short* Wt = (unsigned short*)((char*)d_ws + 2 * g_bytes);
    wt_build<<<32, 256, 0, stream>>>(W1, Wt);
    node_mfma<<<(n_nodes + 63) / 64, 256, 0, stream>>>(z, Wt, b1, gi, gj,
                                                       n_nodes);
    edge_mlp<<<2048, 256, 0, stream>>>(e, gi, gj, W2, b2, out, E);
  } else {
    edge_direct<<<(E + 3) / 4, 256, 0, stream>>>(e, z, W1, b1, W2, b2, out, E);
  }
}

// Round 9
// 129.793 us; speedup vs baseline: 1.1115x; 1.0336x over previous
//
#include <hip/hip_runtime.h>

// MergeLayer: out = sigmoid(relu([z[e0]; z[e1]] @ W1 + b1) @ W2 + b2)
// Factored: g = z @ Wcat (+b1 on gi half)  -- node-level GEMM via bf16 MFMA
//           out[k] = sigmoid(dot(relu(gi[e0]+gj[e1]), W2) + b2)  -- edge gather
//
// Round-9: node_mfma has been ~38us since R0 (inferred R7/R8), 5x off its
// ~8us roofline, at VGPR_Count=136 -- just past the 128-VGPR occupancy cliff
// (waves/SIMD step at 64/128/256): only 3 waves/SIMD + phase barriers +
// fill-swept L3 (cold z reads) = thin latency hiding. Single change: node
// goes 8-wave/512-thread, 2 channel-tiles per wave (acc 32 + a-frags 32 +
// bz 16 ~= 110 VGPR, __launch_bounds__(512,4) enforces 4 waves/SIMD).
// Same 64-node tile, bit-identical numerics; wt_build + edge_mlp verbatim R8.
//
// ws layout: gi (N*128 bf16) | gj (N*128 bf16) | Wt (256x128 bf16, 64KB)

#define DD 128

typedef __attribute__((ext_vector_type(8))) short short8;
typedef __attribute__((ext_vector_type(4))) float floatx4;

static __device__ __forceinline__ unsigned short f2bf(float f) {
  unsigned int u = __builtin_bit_cast(unsigned int, f);
  u += 0x7fffu + ((u >> 16) & 1u);   // round-to-nearest-even
  return (unsigned short)(u >> 16);
}
static __device__ __forceinline__ float bflo(unsigned int u) {
  return __builtin_bit_cast(float, u << 16);
}
static __device__ __forceinline__ float bfhi(unsigned int u) {
  return __builtin_bit_cast(float, u & 0xffff0000u);
}

// ---------- prelude: Wt[c][k] = Wcat[k][c] as bf16 ---------------------------
__global__ __launch_bounds__(256) void wt_build(
    const float* __restrict__ W1, unsigned short* __restrict__ Wt) {
  const int g = blockIdx.x * 256 + threadIdx.x;  // 8192 threads total
  const int c = g >> 5;                          // 0..255
  const int kq = (g & 31) * 4;                   // 0..124
  const float* src = (c < 128) ? (W1 + c) : (W1 + 128 * 128 + (c - 128));
  ushort4 o;
  o.x = f2bf(src[(size_t)(kq + 0) * 128]);
  o.y = f2bf(src[(size_t)(kq + 1) * 128]);
  o.z = f2bf(src[(size_t)(kq + 2) * 128]);
  o.w = f2bf(src[(size_t)(kq + 3) * 128]);
  *(ushort4*)&Wt[c * 128 + kq] = o;
}

// ---------- node GEMM: 512 threads = 8 waves, 2 channel-tiles/wave -----------
// Wave w owns channel tiles t = 2w, 2w+1 (32 channels) for ALL 4 node-tiles.
// t<8 -> gi (w<4), t>=8 -> gj. VGPR ~110 -> 4 waves/SIMD (vs 136 -> 3).
__global__ __launch_bounds__(512, 4) void node_mfma(
    const float* __restrict__ z, const unsigned short* __restrict__ Wt,
    const float* __restrict__ b1, unsigned short* __restrict__ gi,
    unsigned short* __restrict__ gj, int n_nodes) {
  __shared__ __align__(16) unsigned short zb[64 * 136];  // 17.4 KB
  const int tid = threadIdx.x;
  const int nb = blockIdx.x * 64;

  // stage z tile -> bf16 LDS (coalesced float4 reads; 4 per thread)
#pragma unroll
  for (int i = 0; i < 4; ++i) {
    int q = tid + i * 512;            // 2048 float4 = 64 nodes x 32
    int nl = q >> 5;
    int node = nb + nl; if (node >= n_nodes) node = n_nodes - 1;
    float4 v = ((const float4*)z)[(size_t)node * 32 + (q & 31)];
    ushort4 o;
    o.x = f2bf(v.x); o.y = f2bf(v.y); o.z = f2bf(v.z); o.w = f2bf(v.w);
    *(ushort4*)&zb[nl * 136 + (q & 31) * 4] = o;
  }

  const int w = tid >> 6, lane = tid & 63;
  const int l15 = lane & 15, quad = lane >> 4;

  // A fragments (W): t_global = w*2+tt; 8 x 16B L1-hot loads
  short8 a[2][4];
#pragma unroll
  for (int tt = 0; tt < 2; ++tt) {
    const unsigned short* wrow =
        Wt + (size_t)((w * 2 + tt) * 16 + l15) * 128 + quad * 8;
#pragma unroll
    for (int s = 0; s < 4; ++s) a[tt][s] = *(const short8*)(wrow + s * 32);
  }

  floatx4 acc[2][4];  // [tt][nt]
#pragma unroll
  for (int tt = 0; tt < 2; ++tt) {
    floatx4 bias = {0.f, 0.f, 0.f, 0.f};
    if (w < 4) {  // gi half: b1 folded; channel = (w*2+tt)*16 + quad*4 + r
      float4 b4 = *(const float4*)&b1[(w * 2 + tt) * 16 + quad * 4];
      bias[0] = b4.x; bias[1] = b4.y; bias[2] = b4.z; bias[3] = b4.w;
    }
#pragma unroll
    for (int nt = 0; nt < 4; ++nt) acc[tt][nt] = bias;
  }

  __syncthreads();

#pragma unroll
  for (int nt = 0; nt < 4; ++nt) {
    short8 bz[4];  // B[k=quad*8+j][n=lane&15], n -> node
#pragma unroll
    for (int s = 0; s < 4; ++s)
      bz[s] = *(const short8*)&zb[(nt * 16 + l15) * 136 + s * 32 + quad * 8];
#pragma unroll
    for (int tt = 0; tt < 2; ++tt)
#pragma unroll
      for (int s = 0; s < 4; ++s)
        acc[tt][nt] = __builtin_amdgcn_mfma_f32_16x16x32_bf16(
            a[tt][s], bz[s], acc[tt][nt], 0, 0, 0);
  }

  // ---- epilogue: LDS-staged, fully-coalesced stores (R8 scheme, 8 waves) ----
  // C layout: col=l15 -> node (nt*16+l15), row=quad*4+r -> channel
  // (w&3)*32 + tt*16 + quad*4 + r. Waves 0-3 stage gi half, 4-7 stage gj.
  __syncthreads();   // all zb reads done; buffer reusable
#pragma unroll
  for (int half = 0; half < 2; ++half) {
    if ((w >> 2) == half) {
      const int cbase = (w & 3) * 32;
#pragma unroll
      for (int nt = 0; nt < 4; ++nt) {
        const int row = (nt * 16 + l15) * 136;
#pragma unroll
        for (int tt = 0; tt < 2; ++tt) {
          const int c = cbase + tt * 16 + quad * 4;
          ushort4 o;
          o.x = f2bf(acc[tt][nt][0]); o.y = f2bf(acc[tt][nt][1]);
          o.z = f2bf(acc[tt][nt][2]); o.w = f2bf(acc[tt][nt][3]);
          *(ushort4*)&zb[row + c] = o;
        }
      }
    }
    __syncthreads();
    unsigned short* dst = half ? gj : gi;
    // 64 nodes x 128 ch = 8192 ushort; 2 iters x 512 threads x 8 ushort
#pragma unroll
    for (int it = 0; it < 2; ++it) {
      const int u = tid * 8 + it * 4096;
      const int n = u >> 7, c = u & 127;
      const int node = nb + n;
      ushort4 v0 = *(const ushort4*)&zb[n * 136 + c];
      ushort4 v1 = *(const ushort4*)&zb[n * 136 + c + 4];
      if (node < n_nodes) {
        ushort4* gp = (ushort4*)&dst[(size_t)node * 128 + c];
        gp[0] = v0;
        gp[1] = v1;
      }
    }
    __syncthreads();
  }
}

// ---------- edge phase: persistent, 8 lanes per edge, W2 in registers --------
static __device__ __forceinline__ float dot8(uint4 a, uint4 b, float4 w0, float4 w1) {
  float s;
  s = fmaxf(bflo(a.x) + bflo(b.x), 0.f) * w0.x;
  s = fmaf(fmaxf(bfhi(a.x) + bfhi(b.x), 0.f), w0.y, s);
  s = fmaf(fmaxf(bflo(a.y) + bflo(b.y), 0.f), w0.z, s);
  s = fmaf(fmaxf(bfhi(a.y) + bfhi(b.y), 0.f), w0.w, s);
  s = fmaf(fmaxf(bflo(a.z) + bflo(b.z), 0.f), w1.x, s);
  s = fmaf(fmaxf(bfhi(a.z) + bfhi(b.z), 0.f), w1.y, s);
  s = fmaf(fmaxf(bflo(a.w) + bflo(b.w), 0.f), w1.z, s);
  s = fmaf(fmaxf(bfhi(a.w) + bfhi(b.w), 0.f), w1.w, s);
  return s;
}

__global__ __launch_bounds__(256) void edge_mlp(
    const int* __restrict__ e, const unsigned short* __restrict__ gi,
    const unsigned short* __restrict__ gj, const float* __restrict__ W2,
    const float* __restrict__ b2, float* __restrict__ out, int E) {
  const int p = threadIdx.x & 7;
  // W2 chunk for this lane, held in 16 VGPRs (512B table, L2-hot; once/wave)
  const float4* wv = (const float4*)W2;
  const float4 w0 = wv[p * 2],      w1 = wv[p * 2 + 1];
  const float4 w2 = wv[16 + p * 2], w3 = wv[16 + p * 2 + 1];
  const float bias2 = b2[0];

  const int stride = gridDim.x * 32;  // 32 edges per block per iteration
  for (int edge = blockIdx.x * 32 + (threadIdx.x >> 3); edge < E; edge += stride) {
    const int i = e[edge];
    const int j = e[E + edge];
    // 8 lanes x 16B cover each 128B line of the two 256B rows, fully used.
    const uint4* pi = (const uint4*)(gi + (size_t)i * 128);
    const uint4* pj = (const uint4*)(gj + (size_t)j * 128);
    uint4 a0 = pi[p], a1 = pi[8 + p];
    uint4 c0 = pj[p], c1 = pj[8 + p];
    float acc = dot8(a0, c0, w0, w1) + dot8(a1, c1, w2, w3);
    acc += __shfl_xor(acc, 1);
    acc += __shfl_xor(acc, 2);
    acc += __shfl_xor(acc, 4);
    if (p == 0) {
      float x = acc + bias2;
      out[edge] = 1.f / (1.f + __expf(-x));
    }
  }
}

// ---------- fallback (workspace too small): wave per edge ---------------------
__global__ __launch_bounds__(256) void edge_direct(
    const int* __restrict__ e, const float* __restrict__ z,
    const float* __restrict__ W1, const float* __restrict__ b1,
    const float* __restrict__ W2, const float* __restrict__ b2,
    float* __restrict__ out, int E) {
  const int lane = threadIdx.x & 63;
  const int edge = (int)((blockIdx.x * 256u + threadIdx.x) >> 6);
  if (edge >= E) return;
  const int i = e[edge], j = e[E + edge];
  const float* zi = z + (size_t)i * 128;
  const float* zj = z + (size_t)j * 128;
  const int c0 = lane * 2;
  float h0 = b1[c0], h1 = b1[c0 + 1];
  for (int k = 0; k < 128; ++k) {
    float a = zi[k], b = zj[k];
    float2 wt = *(const float2*)&W1[(size_t)k * 128 + c0];
    float2 wb = *(const float2*)&W1[(size_t)(128 + k) * 128 + c0];
    h0 = fmaf(a, wt.x, h0); h1 = fmaf(a, wt.y, h1);
    h0 = fmaf(b, wb.x, h0); h1 = fmaf(b, wb.y, h1);
  }
  float s = fmaxf(h0, 0.f) * W2[c0] + fmaxf(h1, 0.f) * W2[c0 + 1];
#pragma unroll
  for (int off = 1; off < 64; off <<= 1) s += __shfl_xor(s, off);
  if (lane == 0) out[edge] = 1.f / (1.f + __expf(-(s + b2[0])));
}

extern "C" void kernel_launch(void* const* d_in, const int* in_sizes, int n_in,
                              void* d_out, int out_size, void* d_ws, size_t ws_size,
                              hipStream_t stream) {
  const float* z  = (const float*)d_in[0];
  const int*   e  = (const int*)d_in[1];
  const float* W1 = (const float*)d_in[2];
  const float* b1 = (const float*)d_in[3];
  const float* W2 = (const float*)d_in[4];
  const float* b2 = (const float*)d_in[5];
  float* out = (float*)d_out;
  const int n_nodes = in_sizes[0] / DD;  // 50000
  const int E = in_sizes[1] / 2;         // 600000

  const size_t g_bytes = (size_t)n_nodes * DD * sizeof(unsigned short);
  const size_t wt_bytes = 256 * 128 * sizeof(unsigned short);  // 64 KB

  if (ws_size >= 2 * g_bytes + wt_bytes && n_nodes > 0) {
    unsigned short* gi = (unsigned short*)d_ws;
    unsigned short* gj = (unsigned short*)((char*)d_ws + g_bytes);
    unsigned short* Wt = (unsigned short*)((char*)d_ws + 2 * g_bytes);
    wt_build<<<32, 256, 0, stream>>>(W1, Wt);
    node_mfma<<<(n_nodes + 63) / 64, 512, 0, stream>>>(z, Wt, b1, gi, gj,
                                                       n_nodes);
    edge_mlp<<<2048, 256, 0, stream>>>(e, gi, gj, W2, b2, out, E);
  } else {
    edge_direct<<<(E + 3) / 4, 256, 0, stream>>>(e, z, W1, b1, W2, b2, out, E);
  }
}